// Round 8
// baseline (343.079 us; speedup 1.0000x reference)
//
#include <hip/hip_runtime.h>
#include <hip/hip_fp16.h>

#define N_NODES 100000
#define N_EDGES 400000
#define N_GRAPHS 5000
#define NPG 20
#define SCAN_NB 256
#define SCAN_CHUNK ((N_NODES + SCAN_NB - 1) / SCAN_NB)  // 391
#define TAB_STRIDE (256 * 128 + 128)  // halves: T12[256][128] + v[128]
#define F1 8192   // ushorts per K=64 frag array (1024 frags * 8, fp16)
#define F2 16384  // ushorts per K=128 frag array (2048 frags * 8, fp16)
#define NB_ENC ((N_NODES + 255) / 256)   // 391
#define NB_HIST ((N_EDGES + 255) / 256)  // 1563

typedef __attribute__((ext_vector_type(8))) _Float16 f16x8;
typedef __attribute__((ext_vector_type(2))) _Float16 h2;
typedef __attribute__((ext_vector_type(4))) float f32x4;

// 16-lane all-reduce rounds via DPP (VALU, ~4cy latency) instead of
// __shfl_xor (ds_bpermute, ~120cy lgkm latency). Tree is bit-identical to
// the xor butterfly.
#define DPP_QUAD_XOR1 0xB1  // [1,0,3,2]
#define DPP_QUAD_XOR2 0x4E  // [2,3,0,1]
#define DPP_ROW_HALF_MIRROR 0x141
#define DPP_ROW_MIRROR 0x140
template <int CTRL>
__device__ __forceinline__ float dpp_add(float x) {
  int p = __builtin_amdgcn_update_dpp(0, __float_as_int(x), CTRL, 0xf, 0xf, true);
  return x + __int_as_float(p);
}

// ---------------- fused prologue: hist | tabs | prep ------------------------
// (node encode moved to k_fill2 — it now needs perm to write sorted storage)
__global__ __launch_bounds__(256) void k_prologue(
    const float* __restrict__ bool_emb,
    const int* __restrict__ dst, int* __restrict__ cnt,
    const float* __restrict__ Wedge1, const float* __restrict__ Wedge2,
    const float* __restrict__ bond_emb, const float* __restrict__ We,
    const float* __restrict__ be, __half* __restrict__ tabs,
    const float* __restrict__ Wl1, const float* __restrict__ Wr1,
    const float* __restrict__ Wl2, const float* __restrict__ Wr2,
    unsigned short* __restrict__ fr, int* __restrict__ ghist) {
  int b = blockIdx.x, tid = threadIdx.x;
  if (b < NB_HIST) {
    // ---- in-degree histogram ----
    int e = b * 256 + tid;
    if (e >= N_EDGES) return;
    atomicAdd(cnt + dst[e], 1);
  } else if (b == NB_HIST) {
    // ---- fused logit table (fp16): T12[combo*32+bi], v; rows 22..31 = 0 ----
    // also zeroes ghist (used by k_scan1, which runs after this kernel)
    if (tid < 64) ghist[tid] = 0;
    int s = tid >> 7, c = tid & 127;
    const float* W = s ? Wedge2 : Wedge1;
    __half* T12 = tabs + (size_t)s * TAB_STRIDE;
    __half* v   = T12 + 256 * 128;
    float w8 = W[8 * 128 + c], w9 = W[9 * 128 + c];
    v[c] = __float2half(We[0] * w8 + We[1] * w9);
    float cst = be[0] * w8 + be[1] * w9;
    float bond[22];
    for (int bb = 0; bb < 22; bb++) {
      float acc = 0.f;
      #pragma unroll
      for (int k = 0; k < 8; k++) acc += bond_emb[bb * 8 + k] * W[k * 128 + c];
      bond[bb] = acc;
    }
    for (int combo = 0; combo < 8; combo++) {
      float t2 = cst;
      #pragma unroll
      for (int tt = 0; tt < 3; tt++) {
        int bt = (combo >> tt) & 1;
        t2 += bool_emb[bt * 2 + 0] * W[(10 + 2 * tt + 0) * 128 + c];
        t2 += bool_emb[bt * 2 + 1] * W[(10 + 2 * tt + 1) * 128 + c];
      }
      for (int bb = 0; bb < 22; bb++)
        T12[(combo * 32 + bb) * 128 + c] = __float2half(bond[bb] + t2);
      for (int bb = 22; bb < 32; bb++)   // incl. row 255 = zero (invalid slots)
        T12[(combo * 32 + bb) * 128 + c] = __float2half(0.f);
    }
  } else {
    // ---- W -> MFMA B-fragment prep (fp16, 8 halves = 16 B per frag) ----
    int g = (b - (NB_HIST + 1)) * 256 + tid;
    const float* W; int K; unsigned short* base; int fl;
    if (g < 1024)      { W = Wl1; K = 52;  base = fr;               fl = g; }
    else if (g < 2048) { W = Wr1; K = 52;  base = fr + F1;          fl = g - 1024; }
    else if (g < 4096) { W = Wl2; K = 128; base = fr + 2 * F1;      fl = g - 2048; }
    else if (g < 6144) { W = Wr2; K = 128; base = fr + 2 * F1 + F2; fl = g - 4096; }
    else return;
    int l = fl & 63, ctn = fl >> 6;
    int tn = ctn & 7, c = ctn >> 3;
    int n = tn * 16 + (l & 15);
    int kb = c * 32 + (l >> 4) * 8;
    unsigned h8[8];
    #pragma unroll
    for (int j = 0; j < 8; j++) {
      int k = kb + j;
      float v = (k < K) ? W[(size_t)k * 128 + n] : 0.f;
      __half hv = __float2half(v);
      h8[j] = (unsigned)*(unsigned short*)&hv;
    }
    uint4 hv4 = make_uint4(h8[0] | (h8[1] << 16), h8[2] | (h8[3] << 16),
                           h8[4] | (h8[5] << 16), h8[6] | (h8[7] << 16));
    *(uint4*)(base + (size_t)fl * 8) = hv4;
  }
}

// ---------------- scan phase 1: per-chunk sums + degree histogram -----------
__global__ __launch_bounds__(256) void k_scan1(const int* __restrict__ cnt,
                                               int* __restrict__ bsum,
                                               int* __restrict__ ghist) {
  __shared__ int red[256];
  __shared__ int lh[64];
  int b = blockIdx.x, t = threadIdx.x;
  if (t < 64) lh[t] = 0;
  __syncthreads();
  int beg = b * SCAN_CHUNK;
  int end = beg + SCAN_CHUNK; if (end > N_NODES) end = N_NODES;
  int s = 0;
  for (int i = beg + t; i < end; i += 256) {
    int cv = cnt[i];
    s += cv + 1;
    atomicAdd(&lh[cv < 63 ? cv : 63], 1);
  }
  red[t] = s;
  __syncthreads();
  for (int off = 128; off > 0; off >>= 1) {
    if (t < off) red[t] += red[t + off];
    __syncthreads();
  }
  if (t == 0) bsum[b] = red[0];
  if (t < 64 && lh[t] > 0) atomicAdd(&ghist[t], lh[t]);
}

// ---------------- scan phase 2+3 fused: each block re-scans bsum ------------
// Block 0 additionally turns the degree histogram into bucket cursors.
__global__ __launch_bounds__(256) void k_scan3(const int* __restrict__ cnt,
                                               const int* __restrict__ bsum,
                                               int* __restrict__ indptr,
                                               int* __restrict__ cursor,
                                               const int* __restrict__ ghist,
                                               int* __restrict__ gcur) {
  __shared__ int sh[256];
  __shared__ int carry;
  int b = blockIdx.x, t = threadIdx.x;
  sh[t] = bsum[t];
  __syncthreads();
  for (int off = 1; off < 256; off <<= 1) {
    int v = (t >= off) ? sh[t - off] : 0;
    __syncthreads();
    sh[t] += v;
    __syncthreads();
  }
  if (t == 0) carry = (b > 0) ? sh[b - 1] : 0;
  __syncthreads();
  int beg = b * SCAN_CHUNK;
  int end = beg + SCAN_CHUNK; if (end > N_NODES) end = N_NODES;
  for (int base = beg; base < end; base += 256) {
    int i = base + t;
    int v = (i < end) ? cnt[i] + 1 : 0;
    sh[t] = v;
    __syncthreads();
    for (int off = 1; off < 256; off <<= 1) {
      int u = (t >= off) ? sh[t - off] : 0;
      __syncthreads();
      sh[t] += u;
      __syncthreads();
    }
    int excl = sh[t] - v;
    if (i < end) {
      int val = carry + excl;
      indptr[i] = val;
      cursor[i] = val;
    }
    __syncthreads();
    if (t == 255) carry += sh[255];
    __syncthreads();
  }
  if (b == 0 && t == 0) indptr[N_NODES] = N_EDGES + N_NODES;
  if (b == 0) {
    // 64-bucket exclusive scan -> gcur (used by k_perm)
    __syncthreads();
    if (t < 64) sh[t] = ghist[t];
    __syncthreads();
    if (t == 0) {
      int run = 0;
      for (int i = 0; i < 64; i++) { int v = sh[i]; sh[i] = run; run += v; }
    }
    __syncthreads();
    if (t < 64) gcur[t] = sh[t];
  }
}

// ---------------- perm + iperm: counting-sort scatter by in-degree ----------
// Must complete BEFORE k_fill2 (which consumes iperm for scode.x remap).
__global__ void k_perm(const int* __restrict__ cnt, int* __restrict__ gcur,
                       int* __restrict__ perm, int* __restrict__ iperm) {
  __shared__ int lh[64];
  __shared__ int lbase[64];
  int b = blockIdx.x, t = threadIdx.x;
  if (t < 64) lh[t] = 0;
  __syncthreads();
  int n = b * 256 + t;
  bool v = (n < N_NODES);
  int dc = 0, r = 0;
  if (v) {
    int cv = cnt[n];
    dc = cv < 63 ? cv : 63;
    r = atomicAdd(&lh[dc], 1);
  }
  __syncthreads();
  if (t < 64 && lh[t] > 0) lbase[t] = atomicAdd(&gcur[t], lh[t]);
  __syncthreads();
  if (v) {
    int pos = lbase[dc] + r;
    perm[pos] = n;
    iperm[n] = pos;
  }
}

// ---------------- CSR fill (src remapped to sorted rows) + sorted encode ----
// scode: {iperm[src], meta | half(ec)<<16}. Node features h0 are written in
// SORTED storage order (row i = node perm[i]) so the gat/gemm pipeline reads
// and writes fully coalesced streams. Bit-identical values, different layout.
__global__ void k_fill2(const int* __restrict__ srcA,
                        const int* __restrict__ dst,
                        const float* __restrict__ eattr,
                        int* __restrict__ cursor,
                        int2* __restrict__ scode,
                        const int* __restrict__ iperm,
                        const float* __restrict__ x,
                        const float* __restrict__ atom_emb,
                        const float* __restrict__ bool_emb,
                        const float* __restrict__ Wn,
                        const float* __restrict__ bn,
                        const int* __restrict__ perm,
                        __half* __restrict__ h0) {
  int b = blockIdx.x, t = threadIdx.x;
  if (b < NB_HIST) {
    int e = b * 256 + t;
    if (e >= N_EDGES) return;
    const float* r = eattr + (size_t)e * 5;
    int bi = (int)r[0];
    float ec = r[1];
    int combo = (int)r[2] + 2 * (int)r[3] + 4 * (int)r[4];
    unsigned meta = (unsigned)(bi | (combo << 5));
    __half hec = __float2half(ec);
    meta |= ((unsigned)*(unsigned short*)&hec) << 16;
    int d = dst[e];
    int p = atomicAdd(&cursor[d], 1);
    scode[p] = make_int2(iperm[srcA[e]], (int)meta);
  } else {
    // ---- node encoder into sorted storage: row i = node perm[i] ----
    int i = (b - NB_HIST) * 256 + t;
    if (i >= N_NODES) return;
    int n = perm[i];
    const float* xr = x + (size_t)n * 14;
    int ai = (int)xr[0];
    _Float16 hr[64];
    #pragma unroll
    for (int j = 0; j < 16; j++) hr[j] = (_Float16)atom_emb[ai * 16 + j];
    float xc[10];
    #pragma unroll
    for (int k = 0; k < 10; k++) xc[k] = xr[1 + k];
    #pragma unroll
    for (int c = 0; c < 30; c++) {
      float s = bn[c];
      #pragma unroll
      for (int k = 0; k < 10; k++) s += xc[k] * Wn[k * 30 + c];
      hr[16 + c] = (_Float16)s;
    }
    #pragma unroll
    for (int tt = 0; tt < 3; tt++) {
      int bb = (int)xr[11 + tt];
      hr[46 + 2 * tt]     = (_Float16)bool_emb[2 * bb];
      hr[46 + 2 * tt + 1] = (_Float16)bool_emb[2 * bb + 1];
    }
    #pragma unroll
    for (int j = 52; j < 64; j++) hr[j] = (_Float16)0.0f;
    uint4* d4 = (uint4*)(h0 + (size_t)i * 64);
    const uint4* s4 = (const uint4*)hr;
    #pragma unroll
    for (int j = 0; j < 8; j++) d4[j] = s4[j];
  }
}

// ---------------- MFMA dual GEMM, M=16/wave, 64k-chunk LDS, LDS epilogue ----
// (R4: M=32 regressed — occupancy-sensitive. R6: no-LDS regressed — L2 B-reads
// cost more than barriers. This staged M=16 form is the local optimum.)
template <int KPAD>
__global__ __launch_bounds__(256, 4) void k_gemm2m(const __half* __restrict__ A,
                                                   const unsigned short* __restrict__ WfL,
                                                   const unsigned short* __restrict__ WfR,
                                                   const float* __restrict__ bl_,
                                                   const float* __restrict__ br_,
                                                   __half* __restrict__ outl,
                                                   __half* __restrict__ outr) {
  __shared__ unsigned short Bs[2][8192];  // L, R (16 KB each, 64 k's)
  const int tid = threadIdx.x;
  const int wv = tid >> 6, lane = tid & 63;
  const int tw = blockIdx.x * 4 + wv;
  const bool active = (tw < N_NODES / 16);  // tail waves stay for barriers
  const int ml = lane & 15, q = lane >> 4;
  const int m0 = active ? tw * 16 : 0;
  f32x4 accL[8], accR[8];
  #pragma unroll
  for (int t = 0; t < 8; t++) {
    accL[t] = (f32x4){0.f, 0.f, 0.f, 0.f};
    accR[t] = (f32x4){0.f, 0.f, 0.f, 0.f};
  }
  const _Float16* ar0 = (const _Float16*)A + (size_t)(m0 + ml) * KPAD + q * 8;
  constexpr int NC2 = KPAD / 64;
  for (int c2 = 0; c2 < NC2; c2++) {
    #pragma unroll
    for (int i0 = 0; i0 < 1024; i0 += 256) {
      int i = i0 + tid;
      size_t g = ((size_t)c2 * 1024 + i) * 8;
      *(uint4*)(&Bs[0][i * 8]) = *(const uint4*)(WfL + g);
      *(uint4*)(&Bs[1][i * 8]) = *(const uint4*)(WfR + g);
    }
    __syncthreads();
    #pragma unroll
    for (int sub = 0; sub < 2; sub++) {
      f16x8 a = *(const f16x8*)(ar0 + c2 * 64 + sub * 32);
      #pragma unroll
      for (int t = 0; t < 8; t++) {
        int idx = (sub * 512 + t * 64 + lane) * 8;
        f16x8 bL = *(const f16x8*)(&Bs[0][idx]);
        f16x8 bR = *(const f16x8*)(&Bs[1][idx]);
        accL[t] = __builtin_amdgcn_mfma_f32_16x16x32_f16(a, bL, accL[t], 0, 0, 0);
        accR[t] = __builtin_amdgcn_mfma_f32_16x16x32_f16(a, bR, accR[t], 0, 0, 0);
      }
    }
    __syncthreads();
  }
  __syncthreads();
  if (!active) return;
  __half* eb = (__half*)&Bs[0][0] + wv * 2048;  // 16 rows x 128 cols fp16
  const int srow = q * 4;
  const int rrow0 = lane >> 4;
  const int rcol = (lane & 15) * 8;
  // ---- L ----
  #pragma unroll
  for (int t = 0; t < 8; t++) {
    int n = t * 16 + ml;
    float bL = bl_[n];
    #pragma unroll
    for (int r = 0; r < 4; r++)
      eb[(srow + r) * 128 + n] = __float2half(accL[t][r] + bL);
  }
  #pragma unroll
  for (int pp = 0; pp < 4; pp++) {
    uint4 v = *(const uint4*)(eb + pp * 512 + lane * 8);
    *(uint4*)(outl + (size_t)(m0 + pp * 4 + rrow0) * 128 + rcol) = v;
  }
  // ---- R ----
  #pragma unroll
  for (int t = 0; t < 8; t++) {
    int n = t * 16 + ml;
    float bR = br_[n];
    #pragma unroll
    for (int r = 0; r < 4; r++)
      eb[(srow + r) * 128 + n] = __float2half(accR[t][r] + bR);
  }
  #pragma unroll
  for (int pp = 0; pp < 4; pp++) {
    uint4 v = *(const uint4*)(eb + pp * 512 + lane * 8);
    *(uint4*)(outr + (size_t)(m0 + pp * 4 + rrow0) * 128 + rcol) = v;
  }
}

// ---------------- GATv2 edge pass: 16 lanes/node (4 nodes/wave) -------------
// Node features stored in SORTED order: wave's 4 rows are ADJACENT -> xr
// reads / hout writes are 1-KB contiguous streams (was random 256-B chunks
// at 2.4 TB/s effective). perm[] is loaded once per node ONLY for the
// indptr lookup (CSR stays in original node space); xl gathers use the
// pre-remapped scode.x. Descending walk (LPT). Uniform fast path + masked
// boundary path; DPP reductions; depth-2 node-loop pipeline. T12 row 255 = 0
// for invalid slots. Never use unvalidated scode data as an address.
__global__ __launch_bounds__(256) void k_gat(const __half* __restrict__ xl,
                                             const __half* __restrict__ xr,
                                             const int* __restrict__ indptr,
                                             const int2* __restrict__ scode,
                                             const __half* __restrict__ tabs,
                                             const float* __restrict__ att,
                                             const float* __restrict__ bias,
                                             __half* __restrict__ hout,
                                             const int* __restrict__ perm) {
  int wid = (blockIdx.x * 256 + threadIdx.x) >> 6;
  int nw = (gridDim.x * 256) >> 6;
  int lane = threadIdx.x & 63;
  int q4 = lane >> 4;            // quarter (node within wave)
  int c = (lane & 15) * 8;       // 8 channels per lane
  const __half* T12 = tabs;      // 256 x 128 fp16
  uint4 vu_ = *(const uint4*)(tabs + 256 * 128 + c);
  h2 v4[4] = {*reinterpret_cast<h2*>(&vu_.x), *reinterpret_cast<h2*>(&vu_.y),
              *reinterpret_cast<h2*>(&vu_.z), *reinterpret_cast<h2*>(&vu_.w)};
  float4 af0 = *(const float4*)(att + c);
  float4 af1 = *(const float4*)(att + c + 4);
  h2 a4[4] = {{(_Float16)af0.x, (_Float16)af0.y}, {(_Float16)af0.z, (_Float16)af0.w},
              {(_Float16)af1.x, (_Float16)af1.y}, {(_Float16)af1.z, (_Float16)af1.w}};
  float bb[8];
  {
    float4 b0 = *(const float4*)(bias + c);
    float4 b1 = *(const float4*)(bias + c + 4);
    bb[0] = b0.x; bb[1] = b0.y; bb[2] = b0.z; bb[3] = b0.w;
    bb[4] = b1.x; bb[5] = b1.y; bb[6] = b1.z; bb[7] = b1.w;
  }
  const h2 z2 = {(_Float16)0.f, (_Float16)0.f};
  const h2 k2 = {(_Float16)0.2f, (_Float16)0.2f};
  wid = __builtin_amdgcn_readfirstlane(wid);
  const int stride = nw * 4;
  int nb = wid * 4;
  if (nb >= N_NODES) return;
  int row = (N_NODES - 4 - nb) + q4;   // sorted storage row (descending walk)
  int n0 = perm[row];                  // original id, for indptr only
  int bg = indptr[n0], en = indptr[n0 + 1];
  uint4 xru = *(const uint4*)(xr + (size_t)row * 128 + c);
  while (true) {
    // ---- prefetch next node-group's head state (latency hidden by edges) --
    int nb2 = nb + stride;
    bool has2 = (nb2 < N_NODES);
    int row2 = has2 ? (N_NODES - 4 - nb2) + q4 : row;  // clamp to valid
    int np = perm[row2];
    int bg2 = indptr[np];
    int en2 = indptr[np + 1];
    uint4 xru2 = *(const uint4*)(xr + (size_t)row2 * 128 + c);
    // ---- process storage row `row` ----
    int beg = bg, end1 = en - 1;           // end1 = self-loop slot
    h2 xrv[4] = {*reinterpret_cast<h2*>(&xru.x), *reinterpret_cast<h2*>(&xru.y),
                 *reinterpret_cast<h2*>(&xru.z), *reinterpret_cast<h2*>(&xru.w)};
    float denom = 0.f;
    float acc[8] = {0.f, 0.f, 0.f, 0.f, 0.f, 0.f, 0.f, 0.f};
    h2 els[4] = {z2, z2, z2, z2};
    int d = end1 - beg;
    int dmax = d, m2;
    m2 = __shfl_xor(dmax, 16, 64); dmax = dmax > m2 ? dmax : m2;
    m2 = __shfl_xor(dmax, 32, 64); dmax = dmax > m2 ? dmax : m2;
    bool uni = __all(d == dmax) != 0;

    // single always-valid edge, full path (used by the uniform tail)
    auto EDGE1 = [&](int jj) {
      int2 sc = scode[jj];
      uint4 lv = *(const uint4*)(xl + (size_t)sc.x * 128 + c);
      uint4 tv = *(const uint4*)(T12 + (size_t)(sc.y & 255) * 128 + c);
      unsigned short us = (unsigned short)((unsigned)sc.y >> 16);
      _Float16 eh = *reinterpret_cast<_Float16*>(&us);
      h2 xl4[4] = {*reinterpret_cast<h2*>(&lv.x), *reinterpret_cast<h2*>(&lv.y),
                   *reinterpret_cast<h2*>(&lv.z), *reinterpret_cast<h2*>(&lv.w)};
      h2 t4[4] = {*reinterpret_cast<h2*>(&tv.x), *reinterpret_cast<h2*>(&tv.y),
                  *reinterpret_cast<h2*>(&tv.z), *reinterpret_cast<h2*>(&tv.w)};
      h2 eh2 = {eh, eh};
      h2 dd = z2;
      #pragma unroll
      for (int k = 0; k < 4; k++) {
        h2 el = eh2 * v4[k] + t4[k];
        h2 m = xl4[k] + xrv[k] + el;
        h2 l = __builtin_elementwise_max(m, z2) + k2 * __builtin_elementwise_min(m, z2);
        dd += l * a4[k];
        els[k] += el;
      }
      float tt = (float)dd[0] + (float)dd[1];
      tt = dpp_add<DPP_QUAD_XOR1>(tt);
      tt = dpp_add<DPP_QUAD_XOR2>(tt);
      tt = dpp_add<DPP_ROW_HALF_MIRROR>(tt);
      tt = dpp_add<DPP_ROW_MIRROR>(tt);
      float ex = __expf(tt);
      denom += ex;
      #pragma unroll
      for (int k = 0; k < 4; k++) {
        acc[2 * k]     += ex * (float)xl4[k][0];
        acc[2 * k + 1] += ex * (float)xl4[k][1];
      }
    };

    if (uni) {
      // ---- fast path: all 4 quarters have degree dmax; no masking at all --
      int fullit = dmax >> 2, rem = dmax & 3;
      for (int it = 0; it < fullit; it++) {
        int j = beg + it * 4;
        int2 sc4[4]; uint4 lv[4]; uint4 tv[4];
        #pragma unroll
        for (int u = 0; u < 4; u++) sc4[u] = scode[j + u];
        #pragma unroll
        for (int u = 0; u < 4; u++)
          lv[u] = *(const uint4*)(xl + (size_t)sc4[u].x * 128 + c);
        #pragma unroll
        for (int u = 0; u < 4; u++)
          tv[u] = *(const uint4*)(T12 + (size_t)(sc4[u].y & 255) * 128 + c);
        float tt[4]; h2 xlv[4][4];
        #pragma unroll
        for (int u = 0; u < 4; u++) {
          xlv[u][0] = *reinterpret_cast<h2*>(&lv[u].x);
          xlv[u][1] = *reinterpret_cast<h2*>(&lv[u].y);
          xlv[u][2] = *reinterpret_cast<h2*>(&lv[u].z);
          xlv[u][3] = *reinterpret_cast<h2*>(&lv[u].w);
          h2 t4[4] = {*reinterpret_cast<h2*>(&tv[u].x), *reinterpret_cast<h2*>(&tv[u].y),
                      *reinterpret_cast<h2*>(&tv[u].z), *reinterpret_cast<h2*>(&tv[u].w)};
          unsigned short us = (unsigned short)((unsigned)sc4[u].y >> 16);
          _Float16 eh = *reinterpret_cast<_Float16*>(&us);
          h2 eh2 = {eh, eh};
          h2 dd = z2;
          #pragma unroll
          for (int k = 0; k < 4; k++) {
            h2 el = eh2 * v4[k] + t4[k];
            h2 m = xlv[u][k] + xrv[k] + el;
            h2 l = __builtin_elementwise_max(m, z2) + k2 * __builtin_elementwise_min(m, z2);
            dd += l * a4[k];
            els[k] += el;
          }
          tt[u] = (float)dd[0] + (float)dd[1];
        }
        #pragma unroll
        for (int u = 0; u < 4; u++) tt[u] = dpp_add<DPP_QUAD_XOR1>(tt[u]);
        #pragma unroll
        for (int u = 0; u < 4; u++) tt[u] = dpp_add<DPP_QUAD_XOR2>(tt[u]);
        #pragma unroll
        for (int u = 0; u < 4; u++) tt[u] = dpp_add<DPP_ROW_HALF_MIRROR>(tt[u]);
        #pragma unroll
        for (int u = 0; u < 4; u++) tt[u] = dpp_add<DPP_ROW_MIRROR>(tt[u]);
        #pragma unroll
        for (int u = 0; u < 4; u++) {
          float ex = __expf(tt[u]);
          denom += ex;
          #pragma unroll
          for (int k = 0; k < 4; k++) {
            acc[2 * k]     += ex * (float)xlv[u][k][0];
            acc[2 * k + 1] += ex * (float)xlv[u][k][1];
          }
        }
      }
      // tail: exactly rem valid edges, wave-uniform branches
      int j = beg + fullit * 4;
      if (rem > 0) EDGE1(j);
      if (rem > 1) EDGE1(j + 1);
      if (rem > 2) EDGE1(j + 2);
    } else {
      // ---- generic masked path (bucket-boundary groups only, <=64/25000) --
      int last = (end1 > beg) ? end1 - 1 : beg;  // clamp (may be unwritten!)
      int iters = (dmax + 3) >> 2;
      for (int it = 0; it < iters; it++) {
        int j = beg + it * 4;
        int2 sc4[4]; h2 xlv[4][4]; float tt[4];
        bool val[4];
        #pragma unroll
        for (int u = 0; u < 4; u++) {
          val[u] = (j + u < end1);  // uniform within quarter
          int jj = val[u] ? j + u : last;
          sc4[u] = scode[jj];
        }
        #pragma unroll
        for (int u = 0; u < 4; u++) {
          int s = val[u] ? sc4[u].x : row;  // NEVER use poison as an address
          uint4 lv = *(const uint4*)(xl + (size_t)s * 128 + c);
          xlv[u][0] = *reinterpret_cast<h2*>(&lv.x);
          xlv[u][1] = *reinterpret_cast<h2*>(&lv.y);
          xlv[u][2] = *reinterpret_cast<h2*>(&lv.z);
          xlv[u][3] = *reinterpret_cast<h2*>(&lv.w);
        }
        #pragma unroll
        for (int u = 0; u < 4; u++) {
          int meta = val[u] ? (sc4[u].y & 255) : 255;  // row 255 = zeros
          unsigned short us = val[u] ? (unsigned short)((unsigned)sc4[u].y >> 16)
                                     : (unsigned short)0;
          _Float16 eh = *reinterpret_cast<_Float16*>(&us);
          uint4 tv = *(const uint4*)(T12 + (size_t)meta * 128 + c);
          h2 t4[4] = {*reinterpret_cast<h2*>(&tv.x), *reinterpret_cast<h2*>(&tv.y),
                      *reinterpret_cast<h2*>(&tv.z), *reinterpret_cast<h2*>(&tv.w)};
          h2 eh2 = {eh, eh};
          h2 dd = z2;
          #pragma unroll
          for (int k = 0; k < 4; k++) {
            h2 el = eh2 * v4[k] + t4[k];
            h2 m = xlv[u][k] + xrv[k] + el;
            h2 l = __builtin_elementwise_max(m, z2) + k2 * __builtin_elementwise_min(m, z2);
            dd += l * a4[k];
            els[k] += el;  // el=0 for invalid slots — no mask
          }
          tt[u] = (float)dd[0] + (float)dd[1];
        }
        #pragma unroll
        for (int u = 0; u < 4; u++) tt[u] = dpp_add<DPP_QUAD_XOR1>(tt[u]);
        #pragma unroll
        for (int u = 0; u < 4; u++) tt[u] = dpp_add<DPP_QUAD_XOR2>(tt[u]);
        #pragma unroll
        for (int u = 0; u < 4; u++) tt[u] = dpp_add<DPP_ROW_HALF_MIRROR>(tt[u]);
        #pragma unroll
        for (int u = 0; u < 4; u++) tt[u] = dpp_add<DPP_ROW_MIRROR>(tt[u]);
        #pragma unroll
        for (int u = 0; u < 4; u++) {
          float ex = val[u] ? __expf(tt[u]) : 0.f;
          denom += ex;
          #pragma unroll
          for (int k = 0; k < 4; k++) {
            acc[2 * k]     += ex * (float)xlv[u][k][0];
            acc[2 * k + 1] += ex * (float)xlv[u][k][1];
          }
        }
      }
    }
    // self-loop (always present, processed last) — fp32 path
    int cntn = d;
    float inv_cnt = 1.0f / (float)(cntn > 0 ? cntn : 1);
    uint4 xnu = *(const uint4*)(xl + (size_t)row * 128 + c);
    h2 xn[4] = {*reinterpret_cast<h2*>(&xnu.x), *reinterpret_cast<h2*>(&xnu.y),
                *reinterpret_cast<h2*>(&xnu.z), *reinterpret_cast<h2*>(&xnu.w)};
    float afv[8] = {af0.x, af0.y, af0.z, af0.w, af1.x, af1.y, af1.z, af1.w};
    float ts = 0.f;
    float xnf[8];
    #pragma unroll
    for (int k = 0; k < 4; k++) {
      #pragma unroll
      for (int hh = 0; hh < 2; hh++) {
        int i = 2 * k + hh;
        xnf[i] = (float)xn[k][hh];
        float m = xnf[i] + (float)xrv[k][hh] + (float)els[k][hh] * inv_cnt;
        float l = m > 0.f ? m : 0.2f * m;
        ts += l * afv[i];
      }
    }
    ts = dpp_add<DPP_QUAD_XOR1>(ts);
    ts = dpp_add<DPP_QUAD_XOR2>(ts);
    ts = dpp_add<DPP_ROW_HALF_MIRROR>(ts);
    ts = dpp_add<DPP_ROW_MIRROR>(ts);
    float ex = __expf(ts);
    denom += ex;
    #pragma unroll
    for (int i = 0; i < 8; i++) acc[i] += ex * xnf[i];
    float invd = 1.0f / denom;
    h2 p[4];
    #pragma unroll
    for (int k = 0; k < 4; k++) {
      float o0 = acc[2 * k] * invd + bb[2 * k];
      float o1 = acc[2 * k + 1] * invd + bb[2 * k + 1];
      o0 = o0 > 0.f ? o0 : 0.f;
      o1 = o1 > 0.f ? o1 : 0.f;
      p[k] = (h2){(_Float16)o0, (_Float16)o1};
    }
    uint4 st = make_uint4(*reinterpret_cast<unsigned*>(&p[0]),
                          *reinterpret_cast<unsigned*>(&p[1]),
                          *reinterpret_cast<unsigned*>(&p[2]),
                          *reinterpret_cast<unsigned*>(&p[3]));
    *(uint4*)(hout + (size_t)row * 128 + c) = st;
    // ---- advance pipeline ----
    if (!has2) break;
    nb = nb2; row = row2; bg = bg2; en = en2; xru = xru2;
  }
}

// ---------------- readout: global max pool, gather via iperm ---------------
__global__ void k_readout(const __half* __restrict__ h,
                          const int* __restrict__ iperm,
                          float* __restrict__ out) {
  int wid = (blockIdx.x * blockDim.x + threadIdx.x) >> 6;
  int lane = threadIdx.x & 63;
  if (wid >= N_GRAPHS) return;
  int c = lane * 2;
  float m0 = -1e30f, m1 = -1e30f;
  for (int i = 0; i < NPG; i++) {
    int row = iperm[wid * NPG + i];
    unsigned v = *(const unsigned*)(h + (size_t)row * 128 + c);
    h2 f = *reinterpret_cast<h2*>(&v);
    m0 = fmaxf(m0, (float)f[0]);
    m1 = fmaxf(m1, (float)f[1]);
  }
  float2 o; o.x = m0; o.y = m1;
  *(float2*)(out + (size_t)wid * 128 + c) = o;
}

extern "C" void kernel_launch(void* const* d_in, const int* in_sizes, int n_in,
                              void* d_out, int out_size, void* d_ws, size_t ws_size,
                              hipStream_t stream) {
  (void)in_sizes; (void)n_in; (void)out_size; (void)ws_size;
  const float* x        = (const float*)d_in[0];
  const int*   eindex   = (const int*)d_in[1];
  const float* eattr    = (const float*)d_in[2];
  const float* atom_emb = (const float*)d_in[4];
  const float* bond_emb = (const float*)d_in[5];
  const float* bool_emb = (const float*)d_in[6];
  const float* Wn   = (const float*)d_in[7];
  const float* bn   = (const float*)d_in[8];
  const float* We   = (const float*)d_in[9];
  const float* be   = (const float*)d_in[10];
  const float* Wl1  = (const float*)d_in[11];
  const float* bl1  = (const float*)d_in[12];
  const float* Wr1  = (const float*)d_in[13];
  const float* br1  = (const float*)d_in[14];
  const float* Wedge1 = (const float*)d_in[15];
  const float* att1 = (const float*)d_in[16];
  const float* bias1 = (const float*)d_in[17];
  const float* Wl2  = (const float*)d_in[18];
  const float* bl2  = (const float*)d_in[19];
  const float* Wr2  = (const float*)d_in[20];
  const float* br2  = (const float*)d_in[21];
  const float* Wedge2 = (const float*)d_in[22];
  const float* att2 = (const float*)d_in[23];
  const float* bias2 = (const float*)d_in[24];

  const int* srcA = eindex;
  const int* dstA = eindex + N_EDGES;

  char* p = (char*)d_ws;
  auto alloc = [&](size_t bytes) {
    char* r = p;
    p += (bytes + 255) & ~(size_t)255;
    return r;
  };
  __half* h0     = (__half*)alloc((size_t)N_NODES * 64 * 2);
  __half* h      = (__half*)alloc((size_t)N_NODES * 128 * 2);
  __half* xl     = (__half*)alloc((size_t)N_NODES * 128 * 2);
  __half* xrb    = (__half*)alloc((size_t)N_NODES * 128 * 2);
  int*    cnt    = (int*)alloc((size_t)N_NODES * 4);
  int*    indptr = (int*)alloc((size_t)(N_NODES + 1) * 4);
  int*    cursor = (int*)alloc((size_t)N_NODES * 4);
  int2*   scode  = (int2*)alloc((size_t)(N_EDGES + N_NODES) * 8);
  __half* tabs   = (__half*)alloc((size_t)2 * TAB_STRIDE * 2);
  unsigned short* wfrag = (unsigned short*)alloc((size_t)(2 * F1 + 2 * F2) * 2);
  int*    bsum   = (int*)alloc((size_t)SCAN_NB * 4);
  int*    ghist  = (int*)alloc((size_t)64 * 4);
  int*    gcur   = (int*)alloc((size_t)64 * 4);
  int*    perm   = (int*)alloc((size_t)N_NODES * 4);
  int*    iperm  = (int*)alloc((size_t)N_NODES * 4);

  (void)hipMemsetAsync(cnt, 0, (size_t)N_NODES * 4, stream);

  // fused prologue: hist | tabs(+ghist zero) | prep
  k_prologue<<<NB_HIST + 1 + 24, 256, 0, stream>>>(
      bool_emb, dstA, cnt,
      Wedge1, Wedge2, bond_emb, We, be, tabs,
      Wl1, Wr1, Wl2, Wr2, wfrag, ghist);
  k_scan1<<<SCAN_NB, 256, 0, stream>>>(cnt, bsum, ghist);
  k_scan3<<<SCAN_NB, 256, 0, stream>>>(cnt, bsum, indptr, cursor, ghist, gcur);
  k_perm<<<NB_ENC, 256, 0, stream>>>(cnt, gcur, perm, iperm);
  k_fill2<<<NB_HIST + NB_ENC, 256, 0, stream>>>(srcA, dstA, eattr, cursor, scode,
                                                iperm, x, atom_emb, bool_emb,
                                                Wn, bn, perm, h0);

  const unsigned short* f_l1 = wfrag;
  const unsigned short* f_r1 = wfrag + F1;
  const unsigned short* f_l2 = wfrag + 2 * F1;
  const unsigned short* f_r2 = wfrag + 2 * F1 + F2;

  const int GB2 = (N_NODES / 16 + 3) / 4;  // 1563 blocks of 4 waves (M=16)

  // layer 1 (K=52 zero-padded to 64)
  k_gemm2m<64><<<GB2, 256, 0, stream>>>(h0, f_l1, f_r1, bl1, br1, xl, xrb);
  k_gat<<<2048, 256, 0, stream>>>(xl, xrb, indptr, scode, tabs, att1, bias1, h, perm);

  // layer 2 (K=128)
  k_gemm2m<128><<<GB2, 256, 0, stream>>>(h, f_l2, f_r2, bl2, br2, xl, xrb);
  k_gat<<<2048, 256, 0, stream>>>(xl, xrb, indptr, scode, tabs + TAB_STRIDE, att2, bias2, h, perm);

  // layer 3 (shared weights with layer 2)
  k_gemm2m<128><<<GB2, 256, 0, stream>>>(h, f_l2, f_r2, bl2, br2, xl, xrb);
  k_gat<<<2048, 256, 0, stream>>>(xl, xrb, indptr, scode, tabs + TAB_STRIDE, att2, bias2, h, perm);

  k_readout<<<(N_GRAPHS * 64 + 255) / 256, 256, 0, stream>>>(h, iperm, (float*)d_out);
}

// Round 9
// 324.622 us; speedup vs baseline: 1.0569x; 1.0569x over previous
//
#include <hip/hip_runtime.h>
#include <hip/hip_fp16.h>

#define N_NODES 100000
#define N_EDGES 400000
#define N_GRAPHS 5000
#define NPG 20
#define SCAN_NB 256
#define SCAN_CHUNK ((N_NODES + SCAN_NB - 1) / SCAN_NB)  // 391
#define TAB_STRIDE (256 * 128 + 128)  // halves: T12[256][128] + v[128]
#define F1 8192   // ushorts per K=64 frag array (1024 frags * 8, fp16)
#define F2 16384  // ushorts per K=128 frag array (2048 frags * 8, fp16)
#define NB_ENC ((N_NODES + 255) / 256)   // 391
#define NB_HIST ((N_EDGES + 255) / 256)  // 1563

typedef __attribute__((ext_vector_type(8))) _Float16 f16x8;
typedef __attribute__((ext_vector_type(2))) _Float16 h2;
typedef __attribute__((ext_vector_type(4))) float f32x4;
typedef __attribute__((ext_vector_type(2))) float f32x2;

// 16-lane all-reduce rounds via DPP (VALU, ~4cy latency) instead of
// __shfl_xor (ds_bpermute, ~120cy lgkm latency). Tree is bit-identical to
// the xor butterfly.
#define DPP_QUAD_XOR1 0xB1  // [1,0,3,2]
#define DPP_QUAD_XOR2 0x4E  // [2,3,0,1]
#define DPP_ROW_HALF_MIRROR 0x141
#define DPP_ROW_MIRROR 0x140
template <int CTRL>
__device__ __forceinline__ float dpp_add(float x) {
  int p = __builtin_amdgcn_update_dpp(0, __float_as_int(x), CTRL, 0xf, 0xf, true);
  return x + __int_as_float(p);
}

// ---------------- fused prologue: encode_nodes | hist | tabs | prep ---------
__global__ __launch_bounds__(256) void k_prologue(
    const float* __restrict__ x, const float* __restrict__ atom_emb,
    const float* __restrict__ bool_emb, const float* __restrict__ Wn,
    const float* __restrict__ bn, __half* __restrict__ h0,
    const int* __restrict__ dst, int* __restrict__ cnt,
    const float* __restrict__ Wedge1, const float* __restrict__ Wedge2,
    const float* __restrict__ bond_emb, const float* __restrict__ We,
    const float* __restrict__ be, __half* __restrict__ tabs,
    const float* __restrict__ Wl1, const float* __restrict__ Wr1,
    const float* __restrict__ Wl2, const float* __restrict__ Wr2,
    unsigned short* __restrict__ fr, int* __restrict__ ghist) {
  int b = blockIdx.x, tid = threadIdx.x;
  if (b < NB_ENC) {
    // ---- node encoder: h0[N,64] fp16, row built in regs, 8x dwordx4 store --
    int n = b * 256 + tid;
    if (n >= N_NODES) return;
    const float* xr = x + (size_t)n * 14;
    int ai = (int)xr[0];
    _Float16 hr[64];
    #pragma unroll
    for (int j = 0; j < 16; j++) hr[j] = (_Float16)atom_emb[ai * 16 + j];
    float xc[10];
    #pragma unroll
    for (int k = 0; k < 10; k++) xc[k] = xr[1 + k];
    #pragma unroll
    for (int c = 0; c < 30; c++) {
      float s = bn[c];
      #pragma unroll
      for (int k = 0; k < 10; k++) s += xc[k] * Wn[k * 30 + c];
      hr[16 + c] = (_Float16)s;
    }
    #pragma unroll
    for (int t = 0; t < 3; t++) {
      int bb = (int)xr[11 + t];
      hr[46 + 2 * t]     = (_Float16)bool_emb[2 * bb];
      hr[46 + 2 * t + 1] = (_Float16)bool_emb[2 * bb + 1];
    }
    #pragma unroll
    for (int j = 52; j < 64; j++) hr[j] = (_Float16)0.0f;
    uint4* d4 = (uint4*)(h0 + (size_t)n * 64);
    const uint4* s4 = (const uint4*)hr;
    #pragma unroll
    for (int j = 0; j < 8; j++) d4[j] = s4[j];
  } else if (b < NB_ENC + NB_HIST) {
    // ---- in-degree histogram ----
    int e = (b - NB_ENC) * 256 + tid;
    if (e >= N_EDGES) return;
    atomicAdd(cnt + dst[e], 1);
  } else if (b == NB_ENC + NB_HIST) {
    // ---- fused logit table (fp16): T12[combo*32+bi], v; rows 22..31 = 0 ----
    // also zeroes ghist (used by k_scan1, which runs after this kernel)
    if (tid < 64) ghist[tid] = 0;
    int s = tid >> 7, c = tid & 127;
    const float* W = s ? Wedge2 : Wedge1;
    __half* T12 = tabs + (size_t)s * TAB_STRIDE;
    __half* v   = T12 + 256 * 128;
    float w8 = W[8 * 128 + c], w9 = W[9 * 128 + c];
    v[c] = __float2half(We[0] * w8 + We[1] * w9);
    float cst = be[0] * w8 + be[1] * w9;
    float bond[22];
    for (int bb = 0; bb < 22; bb++) {
      float acc = 0.f;
      #pragma unroll
      for (int k = 0; k < 8; k++) acc += bond_emb[bb * 8 + k] * W[k * 128 + c];
      bond[bb] = acc;
    }
    for (int combo = 0; combo < 8; combo++) {
      float t2 = cst;
      #pragma unroll
      for (int tt = 0; tt < 3; tt++) {
        int bt = (combo >> tt) & 1;
        t2 += bool_emb[bt * 2 + 0] * W[(10 + 2 * tt + 0) * 128 + c];
        t2 += bool_emb[bt * 2 + 1] * W[(10 + 2 * tt + 1) * 128 + c];
      }
      for (int bb = 0; bb < 22; bb++)
        T12[(combo * 32 + bb) * 128 + c] = __float2half(bond[bb] + t2);
      for (int bb = 22; bb < 32; bb++)   // incl. row 255 = zero (invalid slots)
        T12[(combo * 32 + bb) * 128 + c] = __float2half(0.f);
    }
  } else {
    // ---- W -> MFMA B-fragment prep (fp16, 8 halves = 16 B per frag) ----
    int g = (b - (NB_ENC + NB_HIST + 1)) * 256 + tid;
    const float* W; int K; unsigned short* base; int fl;
    if (g < 1024)      { W = Wl1; K = 52;  base = fr;               fl = g; }
    else if (g < 2048) { W = Wr1; K = 52;  base = fr + F1;          fl = g - 1024; }
    else if (g < 4096) { W = Wl2; K = 128; base = fr + 2 * F1;      fl = g - 2048; }
    else if (g < 6144) { W = Wr2; K = 128; base = fr + 2 * F1 + F2; fl = g - 4096; }
    else return;
    int l = fl & 63, ctn = fl >> 6;
    int tn = ctn & 7, c = ctn >> 3;
    int n = tn * 16 + (l & 15);
    int kb = c * 32 + (l >> 4) * 8;
    unsigned h8[8];
    #pragma unroll
    for (int j = 0; j < 8; j++) {
      int k = kb + j;
      float v = (k < K) ? W[(size_t)k * 128 + n] : 0.f;
      __half hv = __float2half(v);
      h8[j] = (unsigned)*(unsigned short*)&hv;
    }
    uint4 hv4 = make_uint4(h8[0] | (h8[1] << 16), h8[2] | (h8[3] << 16),
                           h8[4] | (h8[5] << 16), h8[6] | (h8[7] << 16));
    *(uint4*)(base + (size_t)fl * 8) = hv4;
  }
}

// ---------------- scan phase 1: per-chunk sums + degree histogram -----------
__global__ __launch_bounds__(256) void k_scan1(const int* __restrict__ cnt,
                                               int* __restrict__ bsum,
                                               int* __restrict__ ghist) {
  __shared__ int red[256];
  __shared__ int lh[64];
  int b = blockIdx.x, t = threadIdx.x;
  if (t < 64) lh[t] = 0;
  __syncthreads();
  int beg = b * SCAN_CHUNK;
  int end = beg + SCAN_CHUNK; if (end > N_NODES) end = N_NODES;
  int s = 0;
  for (int i = beg + t; i < end; i += 256) {
    int cv = cnt[i];
    s += cv + 1;
    atomicAdd(&lh[cv < 63 ? cv : 63], 1);
  }
  red[t] = s;
  __syncthreads();
  for (int off = 128; off > 0; off >>= 1) {
    if (t < off) red[t] += red[t + off];
    __syncthreads();
  }
  if (t == 0) bsum[b] = red[0];
  if (t < 64 && lh[t] > 0) atomicAdd(&ghist[t], lh[t]);
}

// ---------------- scan phase 2+3 fused: each block re-scans bsum ------------
// Block 0 additionally turns the degree histogram into bucket cursors.
__global__ __launch_bounds__(256) void k_scan3(const int* __restrict__ cnt,
                                               const int* __restrict__ bsum,
                                               int* __restrict__ indptr,
                                               int* __restrict__ cursor,
                                               const int* __restrict__ ghist,
                                               int* __restrict__ gcur) {
  __shared__ int sh[256];
  __shared__ int carry;
  int b = blockIdx.x, t = threadIdx.x;
  sh[t] = bsum[t];
  __syncthreads();
  for (int off = 1; off < 256; off <<= 1) {
    int v = (t >= off) ? sh[t - off] : 0;
    __syncthreads();
    sh[t] += v;
    __syncthreads();
  }
  if (t == 0) carry = (b > 0) ? sh[b - 1] : 0;
  __syncthreads();
  int beg = b * SCAN_CHUNK;
  int end = beg + SCAN_CHUNK; if (end > N_NODES) end = N_NODES;
  for (int base = beg; base < end; base += 256) {
    int i = base + t;
    int v = (i < end) ? cnt[i] + 1 : 0;
    sh[t] = v;
    __syncthreads();
    for (int off = 1; off < 256; off <<= 1) {
      int u = (t >= off) ? sh[t - off] : 0;
      __syncthreads();
      sh[t] += u;
      __syncthreads();
    }
    int excl = sh[t] - v;
    if (i < end) {
      int val = carry + excl;
      indptr[i] = val;
      cursor[i] = val;
    }
    __syncthreads();
    if (t == 255) carry += sh[255];
    __syncthreads();
  }
  if (b == 0 && t == 0) indptr[N_NODES] = N_EDGES + N_NODES;
  if (b == 0) {
    // 64-bucket exclusive scan -> gcur (used by the perm scatter in k_fill)
    __syncthreads();
    if (t < 64) sh[t] = ghist[t];
    __syncthreads();
    if (t == 0) {
      int run = 0;
      for (int i = 0; i < 64; i++) { int v = sh[i]; sh[i] = run; run += v; }
    }
    __syncthreads();
    if (t < 64) gcur[t] = sh[t];
  }
}

// ---------------- CSR fill + degree-sorted node permutation ----------------
// scode packed to int2: {src, meta | half(ec)<<16}. ec was consumed as
// _Float16 in k_gat anyway — converting in fill is bit-identical and halves
// scode traffic.
__global__ void k_fill(const int* __restrict__ srcA,
                       const int* __restrict__ dst,
                       const float* __restrict__ eattr,
                       int* __restrict__ cursor,
                       int2* __restrict__ scode,
                       const int* __restrict__ cnt,
                       int* __restrict__ gcur,
                       int* __restrict__ perm) {
  int b = blockIdx.x, t = threadIdx.x;
  if (b < NB_HIST) {
    int e = b * 256 + t;
    if (e >= N_EDGES) return;
    const float* r = eattr + (size_t)e * 5;
    int bi = (int)r[0];
    float ec = r[1];
    int combo = (int)r[2] + 2 * (int)r[3] + 4 * (int)r[4];
    unsigned meta = (unsigned)(bi | (combo << 5));
    __half hec = __float2half(ec);
    meta |= ((unsigned)*(unsigned short*)&hec) << 16;
    int d = dst[e];
    int p = atomicAdd(&cursor[d], 1);
    scode[p] = make_int2(srcA[e], (int)meta);
  } else {
    __shared__ int lh[64];
    __shared__ int lbase[64];
    if (t < 64) lh[t] = 0;
    __syncthreads();
    int n = (b - NB_HIST) * 256 + t;
    bool v = (n < N_NODES);
    int dc = 0, r = 0;
    if (v) {
      int cv = cnt[n];
      dc = cv < 63 ? cv : 63;
      r = atomicAdd(&lh[dc], 1);
    }
    __syncthreads();
    if (t < 64 && lh[t] > 0) lbase[t] = atomicAdd(&gcur[t], lh[t]);
    __syncthreads();
    if (v) perm[lbase[dc] + r] = n;
  }
}

// ---------------- MFMA dual GEMM, M=16/wave, 64k-chunk LDS, LDS epilogue ----
// (R4: M=32 regressed — occupancy-sensitive. R6: no-LDS regressed — L2 B-reads
// cost more than barriers. This staged M=16 form is the local optimum.)
template <int KPAD>
__global__ __launch_bounds__(256, 4) void k_gemm2m(const __half* __restrict__ A,
                                                   const unsigned short* __restrict__ WfL,
                                                   const unsigned short* __restrict__ WfR,
                                                   const float* __restrict__ bl_,
                                                   const float* __restrict__ br_,
                                                   __half* __restrict__ outl,
                                                   __half* __restrict__ outr) {
  __shared__ unsigned short Bs[2][8192];  // L, R (16 KB each, 64 k's)
  const int tid = threadIdx.x;
  const int wv = tid >> 6, lane = tid & 63;
  const int tw = blockIdx.x * 4 + wv;
  const bool active = (tw < N_NODES / 16);  // tail waves stay for barriers
  const int ml = lane & 15, q = lane >> 4;
  const int m0 = active ? tw * 16 : 0;
  f32x4 accL[8], accR[8];
  #pragma unroll
  for (int t = 0; t < 8; t++) {
    accL[t] = (f32x4){0.f, 0.f, 0.f, 0.f};
    accR[t] = (f32x4){0.f, 0.f, 0.f, 0.f};
  }
  const _Float16* ar0 = (const _Float16*)A + (size_t)(m0 + ml) * KPAD + q * 8;
  constexpr int NC2 = KPAD / 64;
  for (int c2 = 0; c2 < NC2; c2++) {
    #pragma unroll
    for (int i0 = 0; i0 < 1024; i0 += 256) {
      int i = i0 + tid;
      size_t g = ((size_t)c2 * 1024 + i) * 8;
      *(uint4*)(&Bs[0][i * 8]) = *(const uint4*)(WfL + g);
      *(uint4*)(&Bs[1][i * 8]) = *(const uint4*)(WfR + g);
    }
    __syncthreads();
    #pragma unroll
    for (int sub = 0; sub < 2; sub++) {
      f16x8 a = *(const f16x8*)(ar0 + c2 * 64 + sub * 32);
      #pragma unroll
      for (int t = 0; t < 8; t++) {
        int idx = (sub * 512 + t * 64 + lane) * 8;
        f16x8 bL = *(const f16x8*)(&Bs[0][idx]);
        f16x8 bR = *(const f16x8*)(&Bs[1][idx]);
        accL[t] = __builtin_amdgcn_mfma_f32_16x16x32_f16(a, bL, accL[t], 0, 0, 0);
        accR[t] = __builtin_amdgcn_mfma_f32_16x16x32_f16(a, bR, accR[t], 0, 0, 0);
      }
    }
    __syncthreads();
  }
  __syncthreads();
  if (!active) return;
  __half* eb = (__half*)&Bs[0][0] + wv * 2048;  // 16 rows x 128 cols fp16
  const int srow = q * 4;
  const int rrow0 = lane >> 4;
  const int rcol = (lane & 15) * 8;
  // ---- L ----
  #pragma unroll
  for (int t = 0; t < 8; t++) {
    int n = t * 16 + ml;
    float bL = bl_[n];
    #pragma unroll
    for (int r = 0; r < 4; r++)
      eb[(srow + r) * 128 + n] = __float2half(accL[t][r] + bL);
  }
  #pragma unroll
  for (int pp = 0; pp < 4; pp++) {
    uint4 v = *(const uint4*)(eb + pp * 512 + lane * 8);
    *(uint4*)(outl + (size_t)(m0 + pp * 4 + rrow0) * 128 + rcol) = v;
  }
  // ---- R ----
  #pragma unroll
  for (int t = 0; t < 8; t++) {
    int n = t * 16 + ml;
    float bR = br_[n];
    #pragma unroll
    for (int r = 0; r < 4; r++)
      eb[(srow + r) * 128 + n] = __float2half(accR[t][r] + bR);
  }
  #pragma unroll
  for (int pp = 0; pp < 4; pp++) {
    uint4 v = *(const uint4*)(eb + pp * 512 + lane * 8);
    *(uint4*)(outr + (size_t)(m0 + pp * 4 + rrow0) * 128 + rcol) = v;
  }
}

// ---------------- GATv2 edge pass: 16 lanes/node (4 nodes/wave) -------------
// Degree-sorted perm walked in DESCENDING degree order (LPT). Uniform fast
// path (select-free) + masked boundary path; DPP reductions; depth-2
// node-loop pipeline; f32x2 packed accumulate (v_pk_fma_f32 — same IEEE fma
// per component, bit-identical). T12 row 255 = 0 for invalid slots. Never
// use unvalidated scode data as an address.
__global__ __launch_bounds__(256) void k_gat(const __half* __restrict__ xl,
                                             const __half* __restrict__ xr,
                                             const int* __restrict__ indptr,
                                             const int2* __restrict__ scode,
                                             const __half* __restrict__ tabs,
                                             const float* __restrict__ att,
                                             const float* __restrict__ bias,
                                             __half* __restrict__ hout,
                                             const int* __restrict__ perm) {
  int wid = (blockIdx.x * 256 + threadIdx.x) >> 6;
  int nw = (gridDim.x * 256) >> 6;
  int lane = threadIdx.x & 63;
  int q4 = lane >> 4;            // quarter (node within wave)
  int c = (lane & 15) * 8;       // 8 channels per lane
  const __half* T12 = tabs;      // 256 x 128 fp16
  uint4 vu_ = *(const uint4*)(tabs + 256 * 128 + c);
  h2 v4[4] = {*reinterpret_cast<h2*>(&vu_.x), *reinterpret_cast<h2*>(&vu_.y),
              *reinterpret_cast<h2*>(&vu_.z), *reinterpret_cast<h2*>(&vu_.w)};
  float4 af0 = *(const float4*)(att + c);
  float4 af1 = *(const float4*)(att + c + 4);
  h2 a4[4] = {{(_Float16)af0.x, (_Float16)af0.y}, {(_Float16)af0.z, (_Float16)af0.w},
              {(_Float16)af1.x, (_Float16)af1.y}, {(_Float16)af1.z, (_Float16)af1.w}};
  float bb[8];
  {
    float4 b0 = *(const float4*)(bias + c);
    float4 b1 = *(const float4*)(bias + c + 4);
    bb[0] = b0.x; bb[1] = b0.y; bb[2] = b0.z; bb[3] = b0.w;
    bb[4] = b1.x; bb[5] = b1.y; bb[6] = b1.z; bb[7] = b1.w;
  }
  const h2 z2 = {(_Float16)0.f, (_Float16)0.f};
  const h2 k2 = {(_Float16)0.2f, (_Float16)0.2f};
  wid = __builtin_amdgcn_readfirstlane(wid);
  const int stride = nw * 4;
  int nb = wid * 4;
  if (nb >= N_NODES) return;
  int n = perm[(N_NODES - 4 - nb) + q4];  // descending walk (LPT)
  int bg = indptr[n], en = indptr[n + 1];
  uint4 xru = *(const uint4*)(xr + (size_t)n * 128 + c);
  while (true) {
    // ---- prefetch next node-group's head state (latency hidden by edges) --
    int nb2 = nb + stride;
    bool has2 = (nb2 < N_NODES);
    int n2 = has2 ? perm[(N_NODES - 4 - nb2) + q4] : n;  // clamp to valid
    int bg2 = indptr[n2];
    int en2 = indptr[n2 + 1];
    uint4 xru2 = *(const uint4*)(xr + (size_t)n2 * 128 + c);
    // ---- process node n ----
    int beg = bg, end1 = en - 1;           // end1 = self-loop slot
    h2 xrv[4] = {*reinterpret_cast<h2*>(&xru.x), *reinterpret_cast<h2*>(&xru.y),
                 *reinterpret_cast<h2*>(&xru.z), *reinterpret_cast<h2*>(&xru.w)};
    float denom = 0.f;
    f32x2 acc2[4];
    #pragma unroll
    for (int k = 0; k < 4; k++) acc2[k] = (f32x2){0.f, 0.f};
    h2 els[4] = {z2, z2, z2, z2};
    int d = end1 - beg;
    int dmax = d, m2;
    m2 = __shfl_xor(dmax, 16, 64); dmax = dmax > m2 ? dmax : m2;
    m2 = __shfl_xor(dmax, 32, 64); dmax = dmax > m2 ? dmax : m2;
    bool uni = __all(d == dmax) != 0;

    // single always-valid edge, full path (used by the uniform tail)
    auto EDGE1 = [&](int jj) {
      int2 sc = scode[jj];
      uint4 lv = *(const uint4*)(xl + (size_t)sc.x * 128 + c);
      uint4 tv = *(const uint4*)(T12 + (size_t)(sc.y & 255) * 128 + c);
      unsigned short us = (unsigned short)((unsigned)sc.y >> 16);
      _Float16 eh = *reinterpret_cast<_Float16*>(&us);
      h2 xl4[4] = {*reinterpret_cast<h2*>(&lv.x), *reinterpret_cast<h2*>(&lv.y),
                   *reinterpret_cast<h2*>(&lv.z), *reinterpret_cast<h2*>(&lv.w)};
      h2 t4[4] = {*reinterpret_cast<h2*>(&tv.x), *reinterpret_cast<h2*>(&tv.y),
                  *reinterpret_cast<h2*>(&tv.z), *reinterpret_cast<h2*>(&tv.w)};
      h2 eh2 = {eh, eh};
      h2 dd = z2;
      #pragma unroll
      for (int k = 0; k < 4; k++) {
        h2 el = eh2 * v4[k] + t4[k];
        h2 m = xl4[k] + xrv[k] + el;
        h2 l = __builtin_elementwise_max(m, z2) + k2 * __builtin_elementwise_min(m, z2);
        dd += l * a4[k];
        els[k] += el;
      }
      float tt = (float)dd[0] + (float)dd[1];
      tt = dpp_add<DPP_QUAD_XOR1>(tt);
      tt = dpp_add<DPP_QUAD_XOR2>(tt);
      tt = dpp_add<DPP_ROW_HALF_MIRROR>(tt);
      tt = dpp_add<DPP_ROW_MIRROR>(tt);
      float ex = __expf(tt);
      denom += ex;
      f32x2 ex2 = {ex, ex};
      #pragma unroll
      for (int k = 0; k < 4; k++) {
        f32x2 xf = {(float)xl4[k][0], (float)xl4[k][1]};
        acc2[k] += ex2 * xf;
      }
    };

    if (uni) {
      // ---- fast path: all 4 quarters have degree dmax; no masking at all --
      int fullit = dmax >> 2, rem = dmax & 3;
      for (int it = 0; it < fullit; it++) {
        int j = beg + it * 4;
        int2 sc4[4]; uint4 lv[4]; uint4 tv[4];
        #pragma unroll
        for (int u = 0; u < 4; u++) sc4[u] = scode[j + u];
        #pragma unroll
        for (int u = 0; u < 4; u++)
          lv[u] = *(const uint4*)(xl + (size_t)sc4[u].x * 128 + c);
        #pragma unroll
        for (int u = 0; u < 4; u++)
          tv[u] = *(const uint4*)(T12 + (size_t)(sc4[u].y & 255) * 128 + c);
        float tt[4]; h2 xlv[4][4];
        #pragma unroll
        for (int u = 0; u < 4; u++) {
          xlv[u][0] = *reinterpret_cast<h2*>(&lv[u].x);
          xlv[u][1] = *reinterpret_cast<h2*>(&lv[u].y);
          xlv[u][2] = *reinterpret_cast<h2*>(&lv[u].z);
          xlv[u][3] = *reinterpret_cast<h2*>(&lv[u].w);
          h2 t4[4] = {*reinterpret_cast<h2*>(&tv[u].x), *reinterpret_cast<h2*>(&tv[u].y),
                      *reinterpret_cast<h2*>(&tv[u].z), *reinterpret_cast<h2*>(&tv[u].w)};
          unsigned short us = (unsigned short)((unsigned)sc4[u].y >> 16);
          _Float16 eh = *reinterpret_cast<_Float16*>(&us);
          h2 eh2 = {eh, eh};
          h2 dd = z2;
          #pragma unroll
          for (int k = 0; k < 4; k++) {
            h2 el = eh2 * v4[k] + t4[k];
            h2 m = xlv[u][k] + xrv[k] + el;
            h2 l = __builtin_elementwise_max(m, z2) + k2 * __builtin_elementwise_min(m, z2);
            dd += l * a4[k];
            els[k] += el;
          }
          tt[u] = (float)dd[0] + (float)dd[1];
        }
        #pragma unroll
        for (int u = 0; u < 4; u++) tt[u] = dpp_add<DPP_QUAD_XOR1>(tt[u]);
        #pragma unroll
        for (int u = 0; u < 4; u++) tt[u] = dpp_add<DPP_QUAD_XOR2>(tt[u]);
        #pragma unroll
        for (int u = 0; u < 4; u++) tt[u] = dpp_add<DPP_ROW_HALF_MIRROR>(tt[u]);
        #pragma unroll
        for (int u = 0; u < 4; u++) tt[u] = dpp_add<DPP_ROW_MIRROR>(tt[u]);
        #pragma unroll
        for (int u = 0; u < 4; u++) {
          float ex = __expf(tt[u]);
          denom += ex;
          f32x2 ex2 = {ex, ex};
          #pragma unroll
          for (int k = 0; k < 4; k++) {
            f32x2 xf = {(float)xlv[u][k][0], (float)xlv[u][k][1]};
            acc2[k] += ex2 * xf;
          }
        }
      }
      // tail: exactly rem valid edges, wave-uniform branches
      int j = beg + fullit * 4;
      if (rem > 0) EDGE1(j);
      if (rem > 1) EDGE1(j + 1);
      if (rem > 2) EDGE1(j + 2);
    } else {
      // ---- generic masked path (bucket-boundary groups only, <=64/25000) --
      int last = (end1 > beg) ? end1 - 1 : beg;  // clamp (may be unwritten!)
      int iters = (dmax + 3) >> 2;
      for (int it = 0; it < iters; it++) {
        int j = beg + it * 4;
        int2 sc4[4]; h2 xlv[4][4]; float tt[4];
        bool val[4];
        #pragma unroll
        for (int u = 0; u < 4; u++) {
          val[u] = (j + u < end1);  // uniform within quarter
          int jj = val[u] ? j + u : last;
          sc4[u] = scode[jj];
        }
        #pragma unroll
        for (int u = 0; u < 4; u++) {
          int s = val[u] ? sc4[u].x : n;  // NEVER use poison as an address
          uint4 lv = *(const uint4*)(xl + (size_t)s * 128 + c);
          xlv[u][0] = *reinterpret_cast<h2*>(&lv.x);
          xlv[u][1] = *reinterpret_cast<h2*>(&lv.y);
          xlv[u][2] = *reinterpret_cast<h2*>(&lv.z);
          xlv[u][3] = *reinterpret_cast<h2*>(&lv.w);
        }
        #pragma unroll
        for (int u = 0; u < 4; u++) {
          int meta = val[u] ? (sc4[u].y & 255) : 255;  // row 255 = zeros
          unsigned short us = val[u] ? (unsigned short)((unsigned)sc4[u].y >> 16)
                                     : (unsigned short)0;
          _Float16 eh = *reinterpret_cast<_Float16*>(&us);
          uint4 tv = *(const uint4*)(T12 + (size_t)meta * 128 + c);
          h2 t4[4] = {*reinterpret_cast<h2*>(&tv.x), *reinterpret_cast<h2*>(&tv.y),
                      *reinterpret_cast<h2*>(&tv.z), *reinterpret_cast<h2*>(&tv.w)};
          h2 eh2 = {eh, eh};
          h2 dd = z2;
          #pragma unroll
          for (int k = 0; k < 4; k++) {
            h2 el = eh2 * v4[k] + t4[k];
            h2 m = xlv[u][k] + xrv[k] + el;
            h2 l = __builtin_elementwise_max(m, z2) + k2 * __builtin_elementwise_min(m, z2);
            dd += l * a4[k];
            els[k] += el;  // el=0 for invalid slots — no mask
          }
          tt[u] = (float)dd[0] + (float)dd[1];
        }
        #pragma unroll
        for (int u = 0; u < 4; u++) tt[u] = dpp_add<DPP_QUAD_XOR1>(tt[u]);
        #pragma unroll
        for (int u = 0; u < 4; u++) tt[u] = dpp_add<DPP_QUAD_XOR2>(tt[u]);
        #pragma unroll
        for (int u = 0; u < 4; u++) tt[u] = dpp_add<DPP_ROW_HALF_MIRROR>(tt[u]);
        #pragma unroll
        for (int u = 0; u < 4; u++) tt[u] = dpp_add<DPP_ROW_MIRROR>(tt[u]);
        #pragma unroll
        for (int u = 0; u < 4; u++) {
          float ex = val[u] ? __expf(tt[u]) : 0.f;
          denom += ex;
          f32x2 ex2 = {ex, ex};
          #pragma unroll
          for (int k = 0; k < 4; k++) {
            f32x2 xf = {(float)xlv[u][k][0], (float)xlv[u][k][1]};
            acc2[k] += ex2 * xf;
          }
        }
      }
    }
    // self-loop (always present, processed last) — fp32 path
    int cntn = d;
    float inv_cnt = 1.0f / (float)(cntn > 0 ? cntn : 1);
    uint4 xnu = *(const uint4*)(xl + (size_t)n * 128 + c);
    h2 xn[4] = {*reinterpret_cast<h2*>(&xnu.x), *reinterpret_cast<h2*>(&xnu.y),
                *reinterpret_cast<h2*>(&xnu.z), *reinterpret_cast<h2*>(&xnu.w)};
    float afv[8] = {af0.x, af0.y, af0.z, af0.w, af1.x, af1.y, af1.z, af1.w};
    float ts = 0.f;
    float xnf[8];
    #pragma unroll
    for (int k = 0; k < 4; k++) {
      #pragma unroll
      for (int hh = 0; hh < 2; hh++) {
        int i = 2 * k + hh;
        xnf[i] = (float)xn[k][hh];
        float m = xnf[i] + (float)xrv[k][hh] + (float)els[k][hh] * inv_cnt;
        float l = m > 0.f ? m : 0.2f * m;
        ts += l * afv[i];
      }
    }
    ts = dpp_add<DPP_QUAD_XOR1>(ts);
    ts = dpp_add<DPP_QUAD_XOR2>(ts);
    ts = dpp_add<DPP_ROW_HALF_MIRROR>(ts);
    ts = dpp_add<DPP_ROW_MIRROR>(ts);
    float ex = __expf(ts);
    denom += ex;
    {
      f32x2 ex2 = {ex, ex};
      #pragma unroll
      for (int k = 0; k < 4; k++) {
        f32x2 xf = {xnf[2 * k], xnf[2 * k + 1]};
        acc2[k] += ex2 * xf;
      }
    }
    float invd = 1.0f / denom;
    h2 p[4];
    #pragma unroll
    for (int k = 0; k < 4; k++) {
      float o0 = acc2[k][0] * invd + bb[2 * k];
      float o1 = acc2[k][1] * invd + bb[2 * k + 1];
      o0 = o0 > 0.f ? o0 : 0.f;
      o1 = o1 > 0.f ? o1 : 0.f;
      p[k] = (h2){(_Float16)o0, (_Float16)o1};
    }
    uint4 st = make_uint4(*reinterpret_cast<unsigned*>(&p[0]),
                          *reinterpret_cast<unsigned*>(&p[1]),
                          *reinterpret_cast<unsigned*>(&p[2]),
                          *reinterpret_cast<unsigned*>(&p[3]));
    *(uint4*)(hout + (size_t)n * 128 + c) = st;
    // ---- advance pipeline ----
    if (!has2) break;
    nb = nb2; n = n2; bg = bg2; en = en2; xru = xru2;
  }
}

// ---------------- readout: global max pool over 20 contiguous nodes --------
__global__ void k_readout(const __half* __restrict__ h, float* __restrict__ out) {
  int wid = (blockIdx.x * blockDim.x + threadIdx.x) >> 6;
  int lane = threadIdx.x & 63;
  if (wid >= N_GRAPHS) return;
  int c = lane * 2;
  float m0 = -1e30f, m1 = -1e30f;
  for (int i = 0; i < NPG; i++) {
    unsigned v = *(const unsigned*)(h + ((size_t)(wid * NPG + i)) * 128 + c);
    h2 f = *reinterpret_cast<h2*>(&v);
    m0 = fmaxf(m0, (float)f[0]);
    m1 = fmaxf(m1, (float)f[1]);
  }
  float2 o; o.x = m0; o.y = m1;
  *(float2*)(out + (size_t)wid * 128 + c) = o;
}

extern "C" void kernel_launch(void* const* d_in, const int* in_sizes, int n_in,
                              void* d_out, int out_size, void* d_ws, size_t ws_size,
                              hipStream_t stream) {
  (void)in_sizes; (void)n_in; (void)out_size; (void)ws_size;
  const float* x        = (const float*)d_in[0];
  const int*   eindex   = (const int*)d_in[1];
  const float* eattr    = (const float*)d_in[2];
  const float* atom_emb = (const float*)d_in[4];
  const float* bond_emb = (const float*)d_in[5];
  const float* bool_emb = (const float*)d_in[6];
  const float* Wn   = (const float*)d_in[7];
  const float* bn   = (const float*)d_in[8];
  const float* We   = (const float*)d_in[9];
  const float* be   = (const float*)d_in[10];
  const float* Wl1  = (const float*)d_in[11];
  const float* bl1  = (const float*)d_in[12];
  const float* Wr1  = (const float*)d_in[13];
  const float* br1  = (const float*)d_in[14];
  const float* Wedge1 = (const float*)d_in[15];
  const float* att1 = (const float*)d_in[16];
  const float* bias1 = (const float*)d_in[17];
  const float* Wl2  = (const float*)d_in[18];
  const float* bl2  = (const float*)d_in[19];
  const float* Wr2  = (const float*)d_in[20];
  const float* br2  = (const float*)d_in[21];
  const float* Wedge2 = (const float*)d_in[22];
  const float* att2 = (const float*)d_in[23];
  const float* bias2 = (const float*)d_in[24];

  const int* srcA = eindex;
  const int* dstA = eindex + N_EDGES;

  char* p = (char*)d_ws;
  auto alloc = [&](size_t bytes) {
    char* r = p;
    p += (bytes + 255) & ~(size_t)255;
    return r;
  };
  __half* h0     = (__half*)alloc((size_t)N_NODES * 64 * 2);
  __half* h      = (__half*)alloc((size_t)N_NODES * 128 * 2);
  __half* xl     = (__half*)alloc((size_t)N_NODES * 128 * 2);
  __half* xrb    = (__half*)alloc((size_t)N_NODES * 128 * 2);
  int*    cnt    = (int*)alloc((size_t)N_NODES * 4);
  int*    indptr = (int*)alloc((size_t)(N_NODES + 1) * 4);
  int*    cursor = (int*)alloc((size_t)N_NODES * 4);
  int2*   scode  = (int2*)alloc((size_t)(N_EDGES + N_NODES) * 8);
  __half* tabs   = (__half*)alloc((size_t)2 * TAB_STRIDE * 2);
  unsigned short* wfrag = (unsigned short*)alloc((size_t)(2 * F1 + 2 * F2) * 2);
  int*    bsum   = (int*)alloc((size_t)SCAN_NB * 4);
  int*    ghist  = (int*)alloc((size_t)64 * 4);
  int*    gcur   = (int*)alloc((size_t)64 * 4);
  int*    perm   = (int*)alloc((size_t)N_NODES * 4);

  (void)hipMemsetAsync(cnt, 0, (size_t)N_NODES * 4, stream);

  // fused prologue: encode | hist | tabs(+ghist zero) | prep
  k_prologue<<<NB_ENC + NB_HIST + 1 + 24, 256, 0, stream>>>(
      x, atom_emb, bool_emb, Wn, bn, h0, dstA, cnt,
      Wedge1, Wedge2, bond_emb, We, be, tabs,
      Wl1, Wr1, Wl2, Wr2, wfrag, ghist);
  k_scan1<<<SCAN_NB, 256, 0, stream>>>(cnt, bsum, ghist);
  k_scan3<<<SCAN_NB, 256, 0, stream>>>(cnt, bsum, indptr, cursor, ghist, gcur);
  k_fill<<<NB_HIST + NB_ENC, 256, 0, stream>>>(srcA, dstA, eattr, cursor, scode,
                                               cnt, gcur, perm);

  const unsigned short* f_l1 = wfrag;
  const unsigned short* f_r1 = wfrag + F1;
  const unsigned short* f_l2 = wfrag + 2 * F1;
  const unsigned short* f_r2 = wfrag + 2 * F1 + F2;

  const int GB2 = (N_NODES / 16 + 3) / 4;  // 1563 blocks of 4 waves (M=16)

  // layer 1 (K=52 zero-padded to 64)
  k_gemm2m<64><<<GB2, 256, 0, stream>>>(h0, f_l1, f_r1, bl1, br1, xl, xrb);
  k_gat<<<2048, 256, 0, stream>>>(xl, xrb, indptr, scode, tabs, att1, bias1, h, perm);

  // layer 2 (K=128)
  k_gemm2m<128><<<GB2, 256, 0, stream>>>(h, f_l2, f_r2, bl2, br2, xl, xrb);
  k_gat<<<2048, 256, 0, stream>>>(xl, xrb, indptr, scode, tabs + TAB_STRIDE, att2, bias2, h, perm);

  // layer 3 (shared weights with layer 2)
  k_gemm2m<128><<<GB2, 256, 0, stream>>>(h, f_l2, f_r2, bl2, br2, xl, xrb);
  k_gat<<<2048, 256, 0, stream>>>(xl, xrb, indptr, scode, tabs + TAB_STRIDE, att2, bias2, h, perm);

  k_readout<<<(N_GRAPHS * 64 + 255) / 256, 256, 0, stream>>>(h, (float*)d_out);
}